// Round 6
// baseline (304.342 us; speedup 1.0000x reference)
//
#include <hip/hip_runtime.h>

// GCN 3-layer. v6: v5 + rebuilt 64-ch GEMM (64 nodes/block, 4x4 tile/thread,
// k-unroll 4, padded xs to kill LDS bank conflicts).

constexpr int BK_SHIFT = 6;               // 64 nodes per bucket
constexpr int BK_NODES = 64;
constexpr int BK_CAP   = 2432;            // mean 2048 + 8.5 sigma
constexpr int MAXNB    = 1568;

__device__ __forceinline__ unsigned short f2bf(float f) {
    unsigned u = __builtin_bit_cast(unsigned, f);
    u += 0x7FFF + ((u >> 16) & 1);        // round to nearest even
    return (unsigned short)(u >> 16);
}
__device__ __forceinline__ float bf_lo(unsigned d) {
    return __builtin_bit_cast(float, d << 16);
}
__device__ __forceinline__ float bf_hi(unsigned d) {
    return __builtin_bit_cast(float, d & 0xFFFF0000u);
}

__global__ void k_cursor_init(int* __restrict__ cursor, int nb) {
    int i = blockIdx.x * blockDim.x + threadIdx.x;
    if (i < nb) cursor[i] = i * BK_CAP;
}

// 512 threads, 16384 edges/block. LDS-count -> one global claim per
// (block,bucket) -> scatter into claimed contiguous fragment.
__global__ void k_partition(const int* __restrict__ src, const int* __restrict__ dst,
                            int E, int nb, int* __restrict__ cursor,
                            unsigned* __restrict__ inter) {
    __shared__ int lcount[MAXNB];
    __shared__ int gbase[MAXNB];
    int t = threadIdx.x;
    int base = blockIdx.x * 16384;
    for (int i = t; i < MAXNB; i += 512) lcount[i] = 0;
    __syncthreads();
    int sv[32], dvv[32];
#pragma unroll
    for (int j = 0; j < 32; j++) {
        int idx = base + j * 512 + t;
        if (idx < E) {
            sv[j] = src[idx]; dvv[j] = dst[idx];
            atomicAdd(&lcount[dvv[j] >> BK_SHIFT], 1);
        } else dvv[j] = -1;
    }
    __syncthreads();
    for (int i = t; i < nb; i += 512) {
        int c = lcount[i]; int g = 0;
        if (c) g = atomicAdd(&cursor[i], c);
        gbase[i] = g; lcount[i] = 0;
    }
    __syncthreads();
#pragma unroll
    for (int j = 0; j < 32; j++) {
        if (dvv[j] >= 0) {
            int b = dvv[j] >> BK_SHIFT;
            int r = atomicAdd(&lcount[b], 1);
            int pos = gbase[b] + r;
            if (pos < (b + 1) * BK_CAP)
                inter[pos] = (unsigned)sv[j] | ((unsigned)(dvv[j] & (BK_NODES - 1)) << 20);
        }
    }
}

// dinv[d] = rsqrt(indeg+1) from bucket contents
__global__ void k_dinvb(const unsigned* __restrict__ inter, const int* __restrict__ cursor,
                        float* __restrict__ dinv, int N) {
    __shared__ int hist[BK_NODES];
    int t = threadIdx.x, b = blockIdx.x;
    if (t < BK_NODES) hist[t] = 0;
    __syncthreads();
    int start = b * BK_CAP;
    int cnt = min(cursor[b] - start, BK_CAP);
    for (int i = t; i < cnt; i += 256) atomicAdd(&hist[inter[start + i] >> 20], 1);
    __syncthreads();
    if (t < BK_NODES) {
        int d = b * BK_NODES + t;
        if (d < N) dinv[d] = rsqrtf((float)(hist[t] + 1));
    }
}

// ---- GEMM: Hs_bf16[n,64] = dinv[n] * (X[n,K] @ W[K,64]) ----
// 64 nodes x 64 ch per block; thread computes 4 nodes x 4 ch; k-unroll 4.
template <int K>
__global__ __launch_bounds__(256) void k_gemm64bf(const float* __restrict__ X,
                           const float* __restrict__ W,
                           const float* __restrict__ dinv,
                           unsigned short* __restrict__ Y, int n) {
    constexpr int KP = K + 4;             // pad: node stride % 32 banks = 16
    __shared__ float ws[K * 64];
    __shared__ float xs[64 * KP];
    int t = threadIdx.x;
    for (int i = t * 4; i < K * 64; i += 1024)
        *reinterpret_cast<float4*>(&ws[i]) = *reinterpret_cast<const float4*>(W + i);
    int nb = blockIdx.x * 64;
    for (int i = t * 4; i < 64 * K; i += 1024) {
        int r = i / K, c = i % K;
        int node = nb + r;
        float4 v = {0.f, 0.f, 0.f, 0.f};
        if (node < n) v = *reinterpret_cast<const float4*>(X + (size_t)node * K + c);
        *reinterpret_cast<float4*>(&xs[r * KP + c]) = v;
    }
    __syncthreads();
    int ch0 = (t & 15) * 4;
    int nd0 = (t >> 4) * 4;
    float acc[4][4] = {};
    for (int k = 0; k < K; k += 4) {
        float4 xv[4], wv[4];
#pragma unroll
        for (int j = 0; j < 4; j++)
            xv[j] = *reinterpret_cast<const float4*>(&xs[(nd0 + j) * KP + k]);
#pragma unroll
        for (int kk = 0; kk < 4; kk++)
            wv[kk] = *reinterpret_cast<const float4*>(&ws[(k + kk) * 64 + ch0]);
#pragma unroll
        for (int j = 0; j < 4; j++) {
            float xj[4] = {xv[j].x, xv[j].y, xv[j].z, xv[j].w};
#pragma unroll
            for (int kk = 0; kk < 4; kk++) {
                acc[j][0] += xj[kk] * wv[kk].x;
                acc[j][1] += xj[kk] * wv[kk].y;
                acc[j][2] += xj[kk] * wv[kk].z;
                acc[j][3] += xj[kk] * wv[kk].w;
            }
        }
    }
#pragma unroll
    for (int j = 0; j < 4; j++) {
        int gn = nb + nd0 + j;
        if (gn < n) {
            float dv = dinv[gn];
            ushort4 r;
            r.x = f2bf(dv * acc[j][0]); r.y = f2bf(dv * acc[j][1]);
            r.z = f2bf(dv * acc[j][2]); r.w = f2bf(dv * acc[j][3]);
            *reinterpret_cast<ushort4*>(Y + (size_t)gn * 64 + ch0) = r;
        }
    }
}

// ---- GEMM: Hs10_f32[n,10] = dinv[n] * (X[n,64] @ W[64,10]) ----
__global__ void k_gemm10(const float* __restrict__ X, const float* __restrict__ W,
                         const float* __restrict__ dinv, float* __restrict__ Y, int n) {
    __shared__ float ws[64 * 10];
    __shared__ float xs[16 * 64];
    int t = threadIdx.x;
    for (int i = t; i < 640; i += 256) ws[i] = W[i];
    int nb = blockIdx.x * 16;
    for (int i = t; i < 16 * 64; i += 256) {
        int r = i >> 6, c = i & 63;
        int node = nb + r;
        xs[i] = (node < n) ? X[(size_t)node * 64 + c] : 0.f;
    }
    __syncthreads();
    int ns = t >> 4, c = t & 15;
    if (c < 10) {
        float acc = 0.f;
        for (int k = 0; k < 64; k++) acc += xs[ns * 64 + k] * ws[k * 10 + c];
        int node = nb + ns;
        if (node < n) Y[(size_t)node * 10 + c] = dinv[node] * acc;
    }
}

// ---- agg 64ch: block = bucket. Phases: load+hist -> scan -> LDS counting
// sort -> per-node register aggregation (wave/node, 2-deep gather unroll).
__global__ __launch_bounds__(512) void k_agg64(const unsigned short* __restrict__ H,
                        const unsigned* __restrict__ inter, const int* __restrict__ cursor,
                        const float* __restrict__ bias, float* __restrict__ out,
                        int N, int relu) {
    __shared__ unsigned raw[BK_CAP];
    __shared__ unsigned srt[BK_CAP];
    __shared__ int hist[BK_NODES];
    __shared__ int offs[BK_NODES + 1];
    __shared__ int cur[BK_NODES];
    int t = threadIdx.x, b = blockIdx.x;
    if (t < BK_NODES) hist[t] = 0;
    __syncthreads();
    int start = b * BK_CAP;
    int cnt = min(cursor[b] - start, BK_CAP);
    for (int i = t; i < cnt; i += 512) {
        unsigned r = inter[start + i];
        raw[i] = r;
        atomicAdd(&hist[r >> 20], 1);
    }
    __syncthreads();
    if (t < BK_NODES) {                   // wave 0: exclusive scan of 64 bins
        int v = hist[t];
        int inc = v;
#pragma unroll
        for (int d = 1; d < 64; d <<= 1) {
            int o = __shfl_up(inc, d);
            if (t >= d) inc += o;
        }
        offs[t + 1] = inc;
        if (t == 0) offs[0] = 0;
        cur[t] = inc - v;
    }
    __syncthreads();
    for (int i = t; i < cnt; i += 512) {
        unsigned r = raw[i];
        int pos = atomicAdd(&cur[r >> 20], 1);
        srt[pos] = r & 0xFFFFFu;
    }
    __syncthreads();
    int wv = t >> 6, lane = t & 63;
    int esub = lane >> 3, cg = lane & 7;  // 8 edge slots x 8 channel groups
    for (int nd = wv; nd < BK_NODES; nd += 8) {
        int d = b * BK_NODES + nd;
        if (d >= N) break;
        int o0 = offs[nd], o1 = offs[nd + 1];
        float a0 = 0.f, a1 = 0.f, a2 = 0.f, a3 = 0.f;
        float a4 = 0.f, a5 = 0.f, a6 = 0.f, a7 = 0.f;
        int e = o0 + esub;
        for (; e + 8 < o1; e += 16) {     // two independent gathers in flight
            int s0 = srt[e], s1 = srt[e + 8];
            const uint4 v0 = *reinterpret_cast<const uint4*>(H + ((size_t)s0 << 6) + (cg << 3));
            const uint4 v1 = *reinterpret_cast<const uint4*>(H + ((size_t)s1 << 6) + (cg << 3));
            a0 += bf_lo(v0.x); a1 += bf_hi(v0.x); a2 += bf_lo(v0.y); a3 += bf_hi(v0.y);
            a4 += bf_lo(v0.z); a5 += bf_hi(v0.z); a6 += bf_lo(v0.w); a7 += bf_hi(v0.w);
            a0 += bf_lo(v1.x); a1 += bf_hi(v1.x); a2 += bf_lo(v1.y); a3 += bf_hi(v1.y);
            a4 += bf_lo(v1.z); a5 += bf_hi(v1.z); a6 += bf_lo(v1.w); a7 += bf_hi(v1.w);
        }
        if (e < o1) {
            int s0 = srt[e];
            const uint4 v0 = *reinterpret_cast<const uint4*>(H + ((size_t)s0 << 6) + (cg << 3));
            a0 += bf_lo(v0.x); a1 += bf_hi(v0.x); a2 += bf_lo(v0.y); a3 += bf_hi(v0.y);
            a4 += bf_lo(v0.z); a5 += bf_hi(v0.z); a6 += bf_lo(v0.w); a7 += bf_hi(v0.w);
        }
#pragma unroll
        for (int m = 8; m <= 32; m <<= 1) {
            a0 += __shfl_xor(a0, m); a1 += __shfl_xor(a1, m);
            a2 += __shfl_xor(a2, m); a3 += __shfl_xor(a3, m);
            a4 += __shfl_xor(a4, m); a5 += __shfl_xor(a5, m);
            a6 += __shfl_xor(a6, m); a7 += __shfl_xor(a7, m);
        }
        if (esub == 0) {
            float dv = rsqrtf((float)(hist[nd] + 1));
            const uint4 sv = *reinterpret_cast<const uint4*>(H + ((size_t)d << 6) + (cg << 3));
            float s[8] = {bf_lo(sv.x), bf_hi(sv.x), bf_lo(sv.y), bf_hi(sv.y),
                          bf_lo(sv.z), bf_hi(sv.z), bf_lo(sv.w), bf_hi(sv.w)};
            float acc[8] = {a0, a1, a2, a3, a4, a5, a6, a7};
            const float* bp = bias + cg * 8;
            float o[8];
#pragma unroll
            for (int j = 0; j < 8; j++) {
                float val = dv * (acc[j] + s[j]) + bp[j];
                if (relu) val = fmaxf(val, 0.f);
                o[j] = val;
            }
            float4 r0 = {o[0], o[1], o[2], o[3]}, r1 = {o[4], o[5], o[6], o[7]};
            float* op = out + (size_t)d * 64 + cg * 8;
            *reinterpret_cast<float4*>(op)     = r0;
            *reinterpret_cast<float4*>(op + 4) = r1;
        }
    }
}

// ---- agg 10ch f32 (final, no relu) ----
__global__ __launch_bounds__(512) void k_agg10(const float* __restrict__ H,
                        const unsigned* __restrict__ inter, const int* __restrict__ cursor,
                        const float* __restrict__ b3, float* __restrict__ out, int N) {
    __shared__ unsigned raw[BK_CAP];
    __shared__ unsigned srt[BK_CAP];
    __shared__ int hist[BK_NODES];
    __shared__ int offs[BK_NODES + 1];
    __shared__ int cur[BK_NODES];
    int t = threadIdx.x, b = blockIdx.x;
    if (t < BK_NODES) hist[t] = 0;
    __syncthreads();
    int start = b * BK_CAP;
    int cnt = min(cursor[b] - start, BK_CAP);
    for (int i = t; i < cnt; i += 512) {
        unsigned r = inter[start + i];
        raw[i] = r;
        atomicAdd(&hist[r >> 20], 1);
    }
    __syncthreads();
    if (t < BK_NODES) {
        int v = hist[t];
        int inc = v;
#pragma unroll
        for (int d = 1; d < 64; d <<= 1) {
            int o = __shfl_up(inc, d);
            if (t >= d) inc += o;
        }
        offs[t + 1] = inc;
        if (t == 0) offs[0] = 0;
        cur[t] = inc - v;
    }
    __syncthreads();
    for (int i = t; i < cnt; i += 512) {
        unsigned r = raw[i];
        int pos = atomicAdd(&cur[r >> 20], 1);
        srt[pos] = r & 0xFFFFFu;
    }
    __syncthreads();
    int wv = t >> 6, lane = t & 63;
    int esub = lane >> 4, c = lane & 15;  // 4 edge slots x 16 (10 live) channels
    for (int nd = wv; nd < BK_NODES; nd += 8) {
        int d = b * BK_NODES + nd;
        if (d >= N) break;
        int o0 = offs[nd], o1 = offs[nd + 1];
        float acc = 0.f;
        if (c < 10) {
            int e = o0 + esub;
            for (; e + 4 < o1; e += 8) {
                int s0 = srt[e], s1 = srt[e + 4];
                acc += H[(size_t)s0 * 10 + c] + H[(size_t)s1 * 10 + c];
            }
            if (e < o1) acc += H[(size_t)srt[e] * 10 + c];
        }
        acc += __shfl_xor(acc, 16);
        acc += __shfl_xor(acc, 32);
        if (esub == 0 && c < 10) {
            float dv = rsqrtf((float)(hist[nd] + 1));
            out[(size_t)d * 10 + c] = dv * (acc + H[(size_t)d * 10 + c]) + b3[c];
        }
    }
}

extern "C" void kernel_launch(void* const* d_in, const int* in_sizes, int n_in,
                              void* d_out, int out_size, void* d_ws, size_t ws_size,
                              hipStream_t stream) {
    const float* x  = (const float*)d_in[0];
    const int*   ei = (const int*)d_in[1];
    const float* W1 = (const float*)d_in[2];
    const float* b1 = (const float*)d_in[3];
    const float* W2 = (const float*)d_in[4];
    const float* b2 = (const float*)d_in[5];
    const float* W3 = (const float*)d_in[6];
    const float* b3 = (const float*)d_in[7];

    int N = in_sizes[0] / 128;
    int E = in_sizes[1] / 2;
    const int* esrc = ei;
    const int* edst = ei + E;
    int nb = (N + BK_NODES - 1) >> BK_SHIFT;

    char* p = (char*)d_ws;
    auto carve = [&](size_t bytes) -> void* {
        void* r = p;
        p += (bytes + 255) & ~(size_t)255;
        return r;
    };
    int*      cursor = (int*)carve((size_t)MAXNB * 4);
    unsigned* inter  = (unsigned*)carve((size_t)nb * BK_CAP * 4);
    float*    dinv   = (float*)carve((size_t)N * 4);
    unsigned short* Hs = (unsigned short*)carve((size_t)N * 64 * 2);
    float*    G      = (float*)carve((size_t)N * 64 * 4);
    float*    Hs10   = (float*)carve((size_t)N * 10 * 4);
    (void)ws_size; (void)n_in; (void)out_size;

    k_cursor_init<<<(nb + 255) / 256, 256, 0, stream>>>(cursor, nb);
    k_partition<<<(E + 16383) / 16384, 512, 0, stream>>>(esrc, edst, E, nb, cursor, inter);
    k_dinvb<<<nb, 256, 0, stream>>>(inter, cursor, dinv, N);

    // layer 1
    k_gemm64bf<128><<<(N + 63) / 64, 256, 0, stream>>>(x, W1, dinv, Hs, N);
    k_agg64<<<nb, 512, 0, stream>>>(Hs, inter, cursor, b1, G, N, 1);
    // layer 2
    k_gemm64bf<64><<<(N + 63) / 64, 256, 0, stream>>>(G, W2, dinv, Hs, N);
    k_agg64<<<nb, 512, 0, stream>>>(Hs, inter, cursor, b2, G, N, 1);
    // layer 3
    k_gemm10<<<(N + 15) / 16, 256, 0, stream>>>(G, W3, dinv, Hs10, N);
    k_agg10<<<nb, 512, 0, stream>>>(Hs10, inter, cursor, b3, (float*)d_out, N);
}

// Round 7
// 254.146 us; speedup vs baseline: 1.1975x; 1.1975x over previous
//
#include <hip/hip_runtime.h>

// GCN 3-layer. v7: v6 + MFMA bf16 GEMMs (16x16x32, padded-LDS staging) +
// 4-deep gather unroll in aggregation kernels (MLP for latency hiding).

constexpr int BK_SHIFT = 6;               // 64 nodes per bucket
constexpr int BK_NODES = 64;
constexpr int BK_CAP   = 2432;            // mean 2048 + 8.5 sigma
constexpr int MAXNB    = 1568;

typedef __attribute__((ext_vector_type(8))) short short8_t;   // 8 bf16
typedef __attribute__((ext_vector_type(4))) float f32x4_t;    // acc frag

__device__ __forceinline__ unsigned short f2bf(float f) {
    unsigned u = __builtin_bit_cast(unsigned, f);
    u += 0x7FFF + ((u >> 16) & 1);        // round to nearest even
    return (unsigned short)(u >> 16);
}
__device__ __forceinline__ unsigned pack2(float lo, float hi) {
    return (unsigned)f2bf(lo) | ((unsigned)f2bf(hi) << 16);
}
__device__ __forceinline__ float bf_lo(unsigned d) {
    return __builtin_bit_cast(float, d << 16);
}
__device__ __forceinline__ float bf_hi(unsigned d) {
    return __builtin_bit_cast(float, d & 0xFFFF0000u);
}

__global__ void k_cursor_init(int* __restrict__ cursor, int nb) {
    int i = blockIdx.x * blockDim.x + threadIdx.x;
    if (i < nb) cursor[i] = i * BK_CAP;
}

// 512 threads, 16384 edges/block. LDS-count -> one global claim per
// (block,bucket) -> scatter into claimed contiguous fragment.
__global__ void k_partition(const int* __restrict__ src, const int* __restrict__ dst,
                            int E, int nb, int* __restrict__ cursor,
                            unsigned* __restrict__ inter) {
    __shared__ int lcount[MAXNB];
    __shared__ int gbase[MAXNB];
    int t = threadIdx.x;
    int base = blockIdx.x * 16384;
    for (int i = t; i < MAXNB; i += 512) lcount[i] = 0;
    __syncthreads();
    int sv[32], dvv[32];
#pragma unroll
    for (int j = 0; j < 32; j++) {
        int idx = base + j * 512 + t;
        if (idx < E) {
            sv[j] = src[idx]; dvv[j] = dst[idx];
            atomicAdd(&lcount[dvv[j] >> BK_SHIFT], 1);
        } else dvv[j] = -1;
    }
    __syncthreads();
    for (int i = t; i < nb; i += 512) {
        int c = lcount[i]; int g = 0;
        if (c) g = atomicAdd(&cursor[i], c);
        gbase[i] = g; lcount[i] = 0;
    }
    __syncthreads();
#pragma unroll
    for (int j = 0; j < 32; j++) {
        if (dvv[j] >= 0) {
            int b = dvv[j] >> BK_SHIFT;
            int r = atomicAdd(&lcount[b], 1);
            int pos = gbase[b] + r;
            if (pos < (b + 1) * BK_CAP)
                inter[pos] = (unsigned)sv[j] | ((unsigned)(dvv[j] & (BK_NODES - 1)) << 20);
        }
    }
}

// dinv[d] = rsqrt(indeg+1) from bucket contents
__global__ void k_dinvb(const unsigned* __restrict__ inter, const int* __restrict__ cursor,
                        float* __restrict__ dinv, int N) {
    __shared__ int hist[BK_NODES];
    int t = threadIdx.x, b = blockIdx.x;
    if (t < BK_NODES) hist[t] = 0;
    __syncthreads();
    int start = b * BK_CAP;
    int cnt = min(cursor[b] - start, BK_CAP);
    for (int i = t; i < cnt; i += 256) atomicAdd(&hist[inter[start + i] >> 20], 1);
    __syncthreads();
    if (t < BK_NODES) {
        int d = b * BK_NODES + t;
        if (d < N) dinv[d] = rsqrtf((float)(hist[t] + 1));
    }
}

// ---- MFMA GEMM: Hs_bf16[n,64] = dinv[n]*(X[n,K] @ W[K,64]) ----
// 64 nodes x 64 ch per block, 4 waves (wave = 16-row strip), 16x16x32 frags.
// IN_F32: X is f32 (converted during staging); else X is packed bf16.
template <int K, bool IN_F32>
__global__ __launch_bounds__(256) void k_gemmMF(const void* __restrict__ Xv,
                           const float* __restrict__ W,
                           const float* __restrict__ dinv,
                           unsigned short* __restrict__ Y, int n) {
    constexpr int KP = K + 8;             // pad (bf16): row stride 2KP B
    __shared__ unsigned short Al[64 * KP];
    __shared__ unsigned short Bl[64 * KP];
    int t = threadIdx.x;
    int nb = blockIdx.x * 64;
    // stage A (64 x K)
    if (IN_F32) {
        const float* X = (const float*)Xv;
        for (int i = t * 4; i < 64 * K; i += 1024) {
            int r = i / K, c = i % K;
            int node = nb + r;
            float4 v = {0.f, 0.f, 0.f, 0.f};
            if (node < n) v = *reinterpret_cast<const float4*>(X + (size_t)node * K + c);
            uint2 pk = {pack2(v.x, v.y), pack2(v.z, v.w)};
            *reinterpret_cast<uint2*>(&Al[r * KP + c]) = pk;
        }
    } else {
        const unsigned short* X = (const unsigned short*)Xv;
        for (int i = t * 4; i < 64 * K; i += 1024) {
            int r = i / K, c = i % K;
            int node = nb + r;
            uint2 pk = {0u, 0u};
            if (node < n) pk = *reinterpret_cast<const uint2*>(X + (size_t)node * K + c);
            *reinterpret_cast<uint2*>(&Al[r * KP + c]) = pk;
        }
    }
    // stage B transposed: Bl[c*KP + k] = bf16(W[k*64 + c])
    {
        int c = t & 63, kb = t >> 6;
        for (int k = kb; k < K; k += 4)
            Bl[c * KP + k] = f2bf(W[k * 64 + c]);
    }
    __syncthreads();
    int w = t >> 6, lane = t & 63;
    int ml = lane & 15, kg = lane >> 4;
    f32x4_t acc[4] = {{0,0,0,0},{0,0,0,0},{0,0,0,0},{0,0,0,0}};
    for (int ks = 0; ks < K / 32; ks++) {
        int ko = ks * 32 + kg * 8;
        short8_t a = *reinterpret_cast<const short8_t*>(&Al[(16 * w + ml) * KP + ko]);
#pragma unroll
        for (int c = 0; c < 4; c++) {
            short8_t b = *reinterpret_cast<const short8_t*>(&Bl[(16 * c + ml) * KP + ko]);
            acc[c] = __builtin_amdgcn_mfma_f32_16x16x32_bf16(a, b, acc[c], 0, 0, 0);
        }
    }
#pragma unroll
    for (int r = 0; r < 4; r++) {
        int grow = nb + 16 * w + kg * 4 + r;
        if (grow < n) {
            float dv = dinv[grow];
#pragma unroll
            for (int c = 0; c < 4; c++)
                Y[(size_t)grow * 64 + 16 * c + ml] = f2bf(dv * acc[c][r]);
        }
    }
}

// ---- GEMM: Hs10_f32[n,10] = dinv[n] * (X[n,64] @ W[64,10]) ---- (f32 in)
__global__ void k_gemm10(const float* __restrict__ X, const float* __restrict__ W,
                         const float* __restrict__ dinv, float* __restrict__ Y, int n) {
    __shared__ float ws[64 * 10];
    __shared__ float xs[16 * 64];
    int t = threadIdx.x;
    for (int i = t; i < 640; i += 256) ws[i] = W[i];
    int nb = blockIdx.x * 16;
    for (int i = t; i < 16 * 64; i += 256) {
        int r = i >> 6, c = i & 63;
        int node = nb + r;
        xs[i] = (node < n) ? X[(size_t)node * 64 + c] : 0.f;
    }
    __syncthreads();
    int ns = t >> 4, c = t & 15;
    if (c < 10) {
        float acc = 0.f;
        for (int k = 0; k < 64; k++) acc += xs[ns * 64 + k] * ws[k * 10 + c];
        int node = nb + ns;
        if (node < n) Y[(size_t)node * 10 + c] = dinv[node] * acc;
    }
}

// ---- agg 64ch: block = bucket; LDS counting sort -> register aggregation
// with 4-deep gather unroll. OBF: write bf16 (for next MFMA) else f32.
template <int OBF>
__global__ __launch_bounds__(512) void k_agg64(const unsigned short* __restrict__ H,
                        const unsigned* __restrict__ inter, const int* __restrict__ cursor,
                        const float* __restrict__ bias, void* __restrict__ outv,
                        int N, int relu) {
    __shared__ unsigned raw[BK_CAP];
    __shared__ unsigned srt[BK_CAP];
    __shared__ int hist[BK_NODES];
    __shared__ int offs[BK_NODES + 1];
    __shared__ int cur[BK_NODES];
    int t = threadIdx.x, b = blockIdx.x;
    if (t < BK_NODES) hist[t] = 0;
    __syncthreads();
    int start = b * BK_CAP;
    int cnt = min(cursor[b] - start, BK_CAP);
    for (int i = t; i < cnt; i += 512) {
        unsigned r = inter[start + i];
        raw[i] = r;
        atomicAdd(&hist[r >> 20], 1);
    }
    __syncthreads();
    if (t < BK_NODES) {                   // wave 0: exclusive scan of 64 bins
        int v = hist[t];
        int inc = v;
#pragma unroll
        for (int d = 1; d < 64; d <<= 1) {
            int o = __shfl_up(inc, d);
            if (t >= d) inc += o;
        }
        offs[t + 1] = inc;
        if (t == 0) offs[0] = 0;
        cur[t] = inc - v;
    }
    __syncthreads();
    for (int i = t; i < cnt; i += 512) {
        unsigned r = raw[i];
        int pos = atomicAdd(&cur[r >> 20], 1);
        srt[pos] = r & 0xFFFFFu;
    }
    __syncthreads();
    int wv = t >> 6, lane = t & 63;
    int esub = lane >> 3, cg = lane & 7;  // 8 edge slots x 8 channel groups
    const unsigned short* Hc = H + (cg << 3);
    for (int nd = wv; nd < BK_NODES; nd += 8) {
        int d = b * BK_NODES + nd;
        if (d >= N) break;
        int o0 = offs[nd], o1 = offs[nd + 1];
        float a0 = 0.f, a1 = 0.f, a2 = 0.f, a3 = 0.f;
        float a4 = 0.f, a5 = 0.f, a6 = 0.f, a7 = 0.f;
        int e = o0 + esub;
        for (; e + 24 < o1; e += 32) {    // 4 independent gathers in flight
            int s0 = srt[e], s1 = srt[e + 8], s2 = srt[e + 16], s3 = srt[e + 24];
            const uint4 v0 = *reinterpret_cast<const uint4*>(Hc + ((size_t)s0 << 6));
            const uint4 v1 = *reinterpret_cast<const uint4*>(Hc + ((size_t)s1 << 6));
            const uint4 v2 = *reinterpret_cast<const uint4*>(Hc + ((size_t)s2 << 6));
            const uint4 v3 = *reinterpret_cast<const uint4*>(Hc + ((size_t)s3 << 6));
            a0 += bf_lo(v0.x); a1 += bf_hi(v0.x); a2 += bf_lo(v0.y); a3 += bf_hi(v0.y);
            a4 += bf_lo(v0.z); a5 += bf_hi(v0.z); a6 += bf_lo(v0.w); a7 += bf_hi(v0.w);
            a0 += bf_lo(v1.x); a1 += bf_hi(v1.x); a2 += bf_lo(v1.y); a3 += bf_hi(v1.y);
            a4 += bf_lo(v1.z); a5 += bf_hi(v1.z); a6 += bf_lo(v1.w); a7 += bf_hi(v1.w);
            a0 += bf_lo(v2.x); a1 += bf_hi(v2.x); a2 += bf_lo(v2.y); a3 += bf_hi(v2.y);
            a4 += bf_lo(v2.z); a5 += bf_hi(v2.z); a6 += bf_lo(v2.w); a7 += bf_hi(v2.w);
            a0 += bf_lo(v3.x); a1 += bf_hi(v3.x); a2 += bf_lo(v3.y); a3 += bf_hi(v3.y);
            a4 += bf_lo(v3.z); a5 += bf_hi(v3.z); a6 += bf_lo(v3.w); a7 += bf_hi(v3.w);
        }
        for (; e < o1; e += 8) {
            int s0 = srt[e];
            const uint4 v0 = *reinterpret_cast<const uint4*>(Hc + ((size_t)s0 << 6));
            a0 += bf_lo(v0.x); a1 += bf_hi(v0.x); a2 += bf_lo(v0.y); a3 += bf_hi(v0.y);
            a4 += bf_lo(v0.z); a5 += bf_hi(v0.z); a6 += bf_lo(v0.w); a7 += bf_hi(v0.w);
        }
#pragma unroll
        for (int m = 8; m <= 32; m <<= 1) {
            a0 += __shfl_xor(a0, m); a1 += __shfl_xor(a1, m);
            a2 += __shfl_xor(a2, m); a3 += __shfl_xor(a3, m);
            a4 += __shfl_xor(a4, m); a5 += __shfl_xor(a5, m);
            a6 += __shfl_xor(a6, m); a7 += __shfl_xor(a7, m);
        }
        if (esub == 0) {
            float dv = rsqrtf((float)(hist[nd] + 1));
            const uint4 sv = *reinterpret_cast<const uint4*>(Hc + ((size_t)d << 6));
            float s[8] = {bf_lo(sv.x), bf_hi(sv.x), bf_lo(sv.y), bf_hi(sv.y),
                          bf_lo(sv.z), bf_hi(sv.z), bf_lo(sv.w), bf_hi(sv.w)};
            float acc[8] = {a0, a1, a2, a3, a4, a5, a6, a7};
            const float* bp = bias + cg * 8;
            float o[8];
#pragma unroll
            for (int j = 0; j < 8; j++) {
                float val = dv * (acc[j] + s[j]) + bp[j];
                if (relu) val = fmaxf(val, 0.f);
                o[j] = val;
            }
            if (OBF) {
                unsigned short* op = (unsigned short*)outv + (size_t)d * 64 + cg * 8;
                uint4 pk = {pack2(o[0], o[1]), pack2(o[2], o[3]),
                            pack2(o[4], o[5]), pack2(o[6], o[7])};
                *reinterpret_cast<uint4*>(op) = pk;
            } else {
                float* op = (float*)outv + (size_t)d * 64 + cg * 8;
                float4 r0 = {o[0], o[1], o[2], o[3]}, r1 = {o[4], o[5], o[6], o[7]};
                *reinterpret_cast<float4*>(op)     = r0;
                *reinterpret_cast<float4*>(op + 4) = r1;
            }
        }
    }
}

// ---- agg 10ch f32 (final, no relu), 4-deep unroll ----
__global__ __launch_bounds__(512) void k_agg10(const float* __restrict__ H,
                        const unsigned* __restrict__ inter, const int* __restrict__ cursor,
                        const float* __restrict__ b3, float* __restrict__ out, int N) {
    __shared__ unsigned raw[BK_CAP];
    __shared__ unsigned srt[BK_CAP];
    __shared__ int hist[BK_NODES];
    __shared__ int offs[BK_NODES + 1];
    __shared__ int cur[BK_NODES];
    int t = threadIdx.x, b = blockIdx.x;
    if (t < BK_NODES) hist[t] = 0;
    __syncthreads();
    int start = b * BK_CAP;
    int cnt = min(cursor[b] - start, BK_CAP);
    for (int i = t; i < cnt; i += 512) {
        unsigned r = inter[start + i];
        raw[i] = r;
        atomicAdd(&hist[r >> 20], 1);
    }
    __syncthreads();
    if (t < BK_NODES) {
        int v = hist[t];
        int inc = v;
#pragma unroll
        for (int d = 1; d < 64; d <<= 1) {
            int o = __shfl_up(inc, d);
            if (t >= d) inc += o;
        }
        offs[t + 1] = inc;
        if (t == 0) offs[0] = 0;
        cur[t] = inc - v;
    }
    __syncthreads();
    for (int i = t; i < cnt; i += 512) {
        unsigned r = raw[i];
        int pos = atomicAdd(&cur[r >> 20], 1);
        srt[pos] = r & 0xFFFFFu;
    }
    __syncthreads();
    int wv = t >> 6, lane = t & 63;
    int esub = lane >> 4, c = lane & 15;  // 4 edge slots x 16 (10 live) ch
    for (int nd = wv; nd < BK_NODES; nd += 8) {
        int d = b * BK_NODES + nd;
        if (d >= N) break;
        int o0 = offs[nd], o1 = offs[nd + 1];
        float acc = 0.f;
        if (c < 10) {
            int e = o0 + esub;
            for (; e + 12 < o1; e += 16) {
                int s0 = srt[e], s1 = srt[e + 4], s2 = srt[e + 8], s3 = srt[e + 12];
                float h0 = H[(size_t)s0 * 10 + c], h1 = H[(size_t)s1 * 10 + c];
                float h2 = H[(size_t)s2 * 10 + c], h3 = H[(size_t)s3 * 10 + c];
                acc += (h0 + h1) + (h2 + h3);
            }
            for (; e < o1; e += 4) acc += H[(size_t)srt[e] * 10 + c];
        }
        acc += __shfl_xor(acc, 16);
        acc += __shfl_xor(acc, 32);
        if (esub == 0 && c < 10) {
            float dv = rsqrtf((float)(hist[nd] + 1));
            out[(size_t)d * 10 + c] = dv * (acc + H[(size_t)d * 10 + c]) + b3[c];
        }
    }
}

extern "C" void kernel_launch(void* const* d_in, const int* in_sizes, int n_in,
                              void* d_out, int out_size, void* d_ws, size_t ws_size,
                              hipStream_t stream) {
    const float* x  = (const float*)d_in[0];
    const int*   ei = (const int*)d_in[1];
    const float* W1 = (const float*)d_in[2];
    const float* b1 = (const float*)d_in[3];
    const float* W2 = (const float*)d_in[4];
    const float* b2 = (const float*)d_in[5];
    const float* W3 = (const float*)d_in[6];
    const float* b3 = (const float*)d_in[7];

    int N = in_sizes[0] / 128;
    int E = in_sizes[1] / 2;
    const int* esrc = ei;
    const int* edst = ei + E;
    int nb = (N + BK_NODES - 1) >> BK_SHIFT;

    char* p = (char*)d_ws;
    auto carve = [&](size_t bytes) -> void* {
        void* r = p;
        p += (bytes + 255) & ~(size_t)255;
        return r;
    };
    int*      cursor = (int*)carve((size_t)MAXNB * 4);
    unsigned* inter  = (unsigned*)carve((size_t)nb * BK_CAP * 4);
    float*    dinv   = (float*)carve((size_t)N * 4);
    unsigned short* Hs = (unsigned short*)carve((size_t)N * 64 * 2);  // bf16 table
    unsigned short* Gb = (unsigned short*)carve((size_t)N * 64 * 2);  // bf16 agg1 out
    float*    Gf     = (float*)carve((size_t)N * 64 * 4);             // f32 agg2 out
    float*    Hs10   = (float*)carve((size_t)N * 10 * 4);
    (void)ws_size; (void)n_in; (void)out_size;

    k_cursor_init<<<(nb + 255) / 256, 256, 0, stream>>>(cursor, nb);
    k_partition<<<(E + 16383) / 16384, 512, 0, stream>>>(esrc, edst, E, nb, cursor, inter);
    k_dinvb<<<nb, 256, 0, stream>>>(inter, cursor, dinv, N);

    // layer 1: Hs = bf16(dinv*(X @ W1)) ; Gb = bf16(relu(Agg(Hs)+b1))
    k_gemmMF<128, true><<<(N + 63) / 64, 256, 0, stream>>>(x, W1, dinv, Hs, N);
    k_agg64<1><<<nb, 512, 0, stream>>>(Hs, inter, cursor, b1, Gb, N, 1);
    // layer 2: Hs = bf16(dinv*(Gb @ W2)) ; Gf = relu(Agg(Hs)+b2)
    k_gemmMF<64, false><<<(N + 63) / 64, 256, 0, stream>>>(Gb, W2, dinv, Hs, N);
    k_agg64<0><<<nb, 512, 0, stream>>>(Hs, inter, cursor, b2, Gf, N, 1);
    // layer 3
    k_gemm10<<<(N + 15) / 16, 256, 0, stream>>>(Gf, W3, dinv, Hs10, N);
    k_agg10<<<nb, 512, 0, stream>>>(Hs10, inter, cursor, b3, (float*)d_out, N);
}

// Round 8
// 246.026 us; speedup vs baseline: 1.2370x; 1.0330x over previous
//
#include <hip/hip_runtime.h>

// GCN 3-layer. v8: v7 with (a) agg64 reverted to 2-deep gather unroll
// (4-deep was queue-bound regression), (b) bf16 layer-3 table (2MB -> fits
// per-XCD L2), (c) relative cursor via hipMemsetAsync (one fewer dispatch).

constexpr int BK_SHIFT = 6;               // 64 nodes per bucket
constexpr int BK_NODES = 64;
constexpr int BK_CAP   = 2432;            // mean 2048 + 8.5 sigma
constexpr int MAXNB    = 1568;

typedef __attribute__((ext_vector_type(8))) short short8_t;   // 8 bf16
typedef __attribute__((ext_vector_type(4))) float f32x4_t;    // acc frag

__device__ __forceinline__ unsigned short f2bf(float f) {
    unsigned u = __builtin_bit_cast(unsigned, f);
    u += 0x7FFF + ((u >> 16) & 1);        // round to nearest even
    return (unsigned short)(u >> 16);
}
__device__ __forceinline__ unsigned pack2(float lo, float hi) {
    return (unsigned)f2bf(lo) | ((unsigned)f2bf(hi) << 16);
}
__device__ __forceinline__ float bf_lo(unsigned d) {
    return __builtin_bit_cast(float, d << 16);
}
__device__ __forceinline__ float bf_hi(unsigned d) {
    return __builtin_bit_cast(float, d & 0xFFFF0000u);
}
__device__ __forceinline__ float bf1(unsigned short u) {
    return __builtin_bit_cast(float, (unsigned)u << 16);
}

// 512 threads, 16384 edges/block. LDS-count -> one global claim per
// (block,bucket) -> scatter into claimed contiguous fragment.
// cursor[] holds RELATIVE fill counts (memset-0 before launch).
__global__ void k_partition(const int* __restrict__ src, const int* __restrict__ dst,
                            int E, int nb, int* __restrict__ cursor,
                            unsigned* __restrict__ inter) {
    __shared__ int lcount[MAXNB];
    __shared__ int gbase[MAXNB];
    int t = threadIdx.x;
    int base = blockIdx.x * 16384;
    for (int i = t; i < MAXNB; i += 512) lcount[i] = 0;
    __syncthreads();
    int sv[32], dvv[32];
#pragma unroll
    for (int j = 0; j < 32; j++) {
        int idx = base + j * 512 + t;
        if (idx < E) {
            sv[j] = src[idx]; dvv[j] = dst[idx];
            atomicAdd(&lcount[dvv[j] >> BK_SHIFT], 1);
        } else dvv[j] = -1;
    }
    __syncthreads();
    for (int i = t; i < nb; i += 512) {
        int c = lcount[i]; int g = 0;
        if (c) g = atomicAdd(&cursor[i], c);
        gbase[i] = g; lcount[i] = 0;
    }
    __syncthreads();
#pragma unroll
    for (int j = 0; j < 32; j++) {
        if (dvv[j] >= 0) {
            int b = dvv[j] >> BK_SHIFT;
            int r = gbase[b] + atomicAdd(&lcount[b], 1);
            if (r < BK_CAP)
                inter[(size_t)b * BK_CAP + r] =
                    (unsigned)sv[j] | ((unsigned)(dvv[j] & (BK_NODES - 1)) << 20);
        }
    }
}

// dinv[d] = rsqrt(indeg+1) from bucket contents
__global__ void k_dinvb(const unsigned* __restrict__ inter, const int* __restrict__ cursor,
                        float* __restrict__ dinv, int N) {
    __shared__ int hist[BK_NODES];
    int t = threadIdx.x, b = blockIdx.x;
    if (t < BK_NODES) hist[t] = 0;
    __syncthreads();
    int cnt = min(cursor[b], BK_CAP);
    const unsigned* ip = inter + (size_t)b * BK_CAP;
    for (int i = t; i < cnt; i += 256) atomicAdd(&hist[ip[i] >> 20], 1);
    __syncthreads();
    if (t < BK_NODES) {
        int d = b * BK_NODES + t;
        if (d < N) dinv[d] = rsqrtf((float)(hist[t] + 1));
    }
}

// ---- MFMA GEMM: Hs_bf16[n,64] = dinv[n]*(X[n,K] @ W[K,64]) ----
template <int K, bool IN_F32>
__global__ __launch_bounds__(256) void k_gemmMF(const void* __restrict__ Xv,
                           const float* __restrict__ W,
                           const float* __restrict__ dinv,
                           unsigned short* __restrict__ Y, int n) {
    constexpr int KP = K + 8;
    __shared__ unsigned short Al[64 * KP];
    __shared__ unsigned short Bl[64 * KP];
    int t = threadIdx.x;
    int nb = blockIdx.x * 64;
    if (IN_F32) {
        const float* X = (const float*)Xv;
        for (int i = t * 4; i < 64 * K; i += 1024) {
            int r = i / K, c = i % K;
            int node = nb + r;
            float4 v = {0.f, 0.f, 0.f, 0.f};
            if (node < n) v = *reinterpret_cast<const float4*>(X + (size_t)node * K + c);
            uint2 pk = {pack2(v.x, v.y), pack2(v.z, v.w)};
            *reinterpret_cast<uint2*>(&Al[r * KP + c]) = pk;
        }
    } else {
        const unsigned short* X = (const unsigned short*)Xv;
        for (int i = t * 4; i < 64 * K; i += 1024) {
            int r = i / K, c = i % K;
            int node = nb + r;
            uint2 pk = {0u, 0u};
            if (node < n) pk = *reinterpret_cast<const uint2*>(X + (size_t)node * K + c);
            *reinterpret_cast<uint2*>(&Al[r * KP + c]) = pk;
        }
    }
    {
        int c = t & 63, kb = t >> 6;
        for (int k = kb; k < K; k += 4)
            Bl[c * KP + k] = f2bf(W[k * 64 + c]);
    }
    __syncthreads();
    int w = t >> 6, lane = t & 63;
    int ml = lane & 15, kg = lane >> 4;
    f32x4_t acc[4] = {{0,0,0,0},{0,0,0,0},{0,0,0,0},{0,0,0,0}};
    for (int ks = 0; ks < K / 32; ks++) {
        int ko = ks * 32 + kg * 8;
        short8_t a = *reinterpret_cast<const short8_t*>(&Al[(16 * w + ml) * KP + ko]);
#pragma unroll
        for (int c = 0; c < 4; c++) {
            short8_t b = *reinterpret_cast<const short8_t*>(&Bl[(16 * c + ml) * KP + ko]);
            acc[c] = __builtin_amdgcn_mfma_f32_16x16x32_bf16(a, b, acc[c], 0, 0, 0);
        }
    }
#pragma unroll
    for (int r = 0; r < 4; r++) {
        int grow = nb + 16 * w + kg * 4 + r;
        if (grow < n) {
            float dv = dinv[grow];
#pragma unroll
            for (int c = 0; c < 4; c++)
                Y[(size_t)grow * 64 + 16 * c + ml] = f2bf(dv * acc[c][r]);
        }
    }
}

// ---- GEMM: Hs10_bf16[n,10] = bf16(dinv[n] * (X[n,64] @ W[64,10])) ----
__global__ void k_gemm10(const float* __restrict__ X, const float* __restrict__ W,
                         const float* __restrict__ dinv, unsigned short* __restrict__ Y, int n) {
    __shared__ float ws[64 * 10];
    __shared__ float xs[16 * 64];
    int t = threadIdx.x;
    for (int i = t; i < 640; i += 256) ws[i] = W[i];
    int nb = blockIdx.x * 16;
    for (int i = t; i < 16 * 64; i += 256) {
        int r = i >> 6, c = i & 63;
        int node = nb + r;
        xs[i] = (node < n) ? X[(size_t)node * 64 + c] : 0.f;
    }
    __syncthreads();
    int ns = t >> 4, c = t & 15;
    if (c < 10) {
        float acc = 0.f;
        for (int k = 0; k < 64; k++) acc += xs[ns * 64 + k] * ws[k * 10 + c];
        int node = nb + ns;
        if (node < n) Y[(size_t)node * 10 + c] = f2bf(dinv[node] * acc);
    }
}

// ---- agg 64ch: LDS counting sort -> register aggregation, 2-deep unroll.
// OBF: write bf16 (feeds next MFMA) else f32.
template <int OBF>
__global__ __launch_bounds__(512) void k_agg64(const unsigned short* __restrict__ H,
                        const unsigned* __restrict__ inter, const int* __restrict__ cursor,
                        const float* __restrict__ bias, void* __restrict__ outv,
                        int N, int relu) {
    __shared__ unsigned raw[BK_CAP];
    __shared__ unsigned srt[BK_CAP];
    __shared__ int hist[BK_NODES];
    __shared__ int offs[BK_NODES + 1];
    __shared__ int cur[BK_NODES];
    int t = threadIdx.x, b = blockIdx.x;
    if (t < BK_NODES) hist[t] = 0;
    __syncthreads();
    int cnt = min(cursor[b], BK_CAP);
    const unsigned* ip = inter + (size_t)b * BK_CAP;
    for (int i = t; i < cnt; i += 512) {
        unsigned r = ip[i];
        raw[i] = r;
        atomicAdd(&hist[r >> 20], 1);
    }
    __syncthreads();
    if (t < BK_NODES) {
        int v = hist[t];
        int inc = v;
#pragma unroll
        for (int d = 1; d < 64; d <<= 1) {
            int o = __shfl_up(inc, d);
            if (t >= d) inc += o;
        }
        offs[t + 1] = inc;
        if (t == 0) offs[0] = 0;
        cur[t] = inc - v;
    }
    __syncthreads();
    for (int i = t; i < cnt; i += 512) {
        unsigned r = raw[i];
        int pos = atomicAdd(&cur[r >> 20], 1);
        srt[pos] = r & 0xFFFFFu;
    }
    __syncthreads();
    int wv = t >> 6, lane = t & 63;
    int esub = lane >> 3, cg = lane & 7;  // 8 edge slots x 8 channel groups
    const unsigned short* Hc = H + (cg << 3);
    for (int nd = wv; nd < BK_NODES; nd += 8) {
        int d = b * BK_NODES + nd;
        if (d >= N) break;
        int o0 = offs[nd], o1 = offs[nd + 1];
        float a0 = 0.f, a1 = 0.f, a2 = 0.f, a3 = 0.f;
        float a4 = 0.f, a5 = 0.f, a6 = 0.f, a7 = 0.f;
        int e = o0 + esub;
        for (; e + 8 < o1; e += 16) {     // two independent gathers in flight
            int s0 = srt[e], s1 = srt[e + 8];
            const uint4 v0 = *reinterpret_cast<const uint4*>(Hc + ((size_t)s0 << 6));
            const uint4 v1 = *reinterpret_cast<const uint4*>(Hc + ((size_t)s1 << 6));
            a0 += bf_lo(v0.x); a1 += bf_hi(v0.x); a2 += bf_lo(v0.y); a3 += bf_hi(v0.y);
            a4 += bf_lo(v0.z); a5 += bf_hi(v0.z); a6 += bf_lo(v0.w); a7 += bf_hi(v0.w);
            a0 += bf_lo(v1.x); a1 += bf_hi(v1.x); a2 += bf_lo(v1.y); a3 += bf_hi(v1.y);
            a4 += bf_lo(v1.z); a5 += bf_hi(v1.z); a6 += bf_lo(v1.w); a7 += bf_hi(v1.w);
        }
        for (; e < o1; e += 8) {
            int s0 = srt[e];
            const uint4 v0 = *reinterpret_cast<const uint4*>(Hc + ((size_t)s0 << 6));
            a0 += bf_lo(v0.x); a1 += bf_hi(v0.x); a2 += bf_lo(v0.y); a3 += bf_hi(v0.y);
            a4 += bf_lo(v0.z); a5 += bf_hi(v0.z); a6 += bf_lo(v0.w); a7 += bf_hi(v0.w);
        }
#pragma unroll
        for (int m = 8; m <= 32; m <<= 1) {
            a0 += __shfl_xor(a0, m); a1 += __shfl_xor(a1, m);
            a2 += __shfl_xor(a2, m); a3 += __shfl_xor(a3, m);
            a4 += __shfl_xor(a4, m); a5 += __shfl_xor(a5, m);
            a6 += __shfl_xor(a6, m); a7 += __shfl_xor(a7, m);
        }
        if (esub == 0) {
            float dv = rsqrtf((float)(hist[nd] + 1));
            const uint4 sv = *reinterpret_cast<const uint4*>(Hc + ((size_t)d << 6));
            float s[8] = {bf_lo(sv.x), bf_hi(sv.x), bf_lo(sv.y), bf_hi(sv.y),
                          bf_lo(sv.z), bf_hi(sv.z), bf_lo(sv.w), bf_hi(sv.w)};
            float acc[8] = {a0, a1, a2, a3, a4, a5, a6, a7};
            const float* bp = bias + cg * 8;
            float o[8];
#pragma unroll
            for (int j = 0; j < 8; j++) {
                float val = dv * (acc[j] + s[j]) + bp[j];
                if (relu) val = fmaxf(val, 0.f);
                o[j] = val;
            }
            if (OBF) {
                unsigned short* op = (unsigned short*)outv + (size_t)d * 64 + cg * 8;
                uint4 pk = {pack2(o[0], o[1]), pack2(o[2], o[3]),
                            pack2(o[4], o[5]), pack2(o[6], o[7])};
                *reinterpret_cast<uint4*>(op) = pk;
            } else {
                float* op = (float*)outv + (size_t)d * 64 + cg * 8;
                float4 r0 = {o[0], o[1], o[2], o[3]}, r1 = {o[4], o[5], o[6], o[7]};
                *reinterpret_cast<float4*>(op)     = r0;
                *reinterpret_cast<float4*>(op + 4) = r1;
            }
        }
    }
}

// ---- agg 10ch (final, no relu): bf16 table (2MB, L2-resident), f32 out ----
__global__ __launch_bounds__(512) void k_agg10(const unsigned short* __restrict__ H,
                        const unsigned* __restrict__ inter, const int* __restrict__ cursor,
                        const float* __restrict__ b3, float* __restrict__ out, int N) {
    __shared__ unsigned raw[BK_CAP];
    __shared__ unsigned srt[BK_CAP];
    __shared__ int hist[BK_NODES];
    __shared__ int offs[BK_NODES + 1];
    __shared__ int cur[BK_NODES];
    int t = threadIdx.x, b = blockIdx.x;
    if (t < BK_NODES) hist[t] = 0;
    __syncthreads();
    int cnt = min(cursor[b], BK_CAP);
    const unsigned* ip = inter + (size_t)b * BK_CAP;
    for (int i = t; i < cnt; i += 512) {
        unsigned r = ip[i];
        raw[i] = r;
        atomicAdd(&hist[r >> 20], 1);
    }
    __syncthreads();
    if (t < BK_NODES) {
        int v = hist[t];
        int inc = v;
#pragma unroll
        for (int d = 1; d < 64; d <<= 1) {
            int o = __shfl_up(inc, d);
            if (t >= d) inc += o;
        }
        offs[t + 1] = inc;
        if (t == 0) offs[0] = 0;
        cur[t] = inc - v;
    }
    __syncthreads();
    for (int i = t; i < cnt; i += 512) {
        unsigned r = raw[i];
        int pos = atomicAdd(&cur[r >> 20], 1);
        srt[pos] = r & 0xFFFFFu;
    }
    __syncthreads();
    int wv = t >> 6, lane = t & 63;
    int esub = lane >> 4, c = lane & 15;  // 4 edge slots x 16 (10 live) ch
    for (int nd = wv; nd < BK_NODES; nd += 8) {
        int d = b * BK_NODES + nd;
        if (d >= N) break;
        int o0 = offs[nd], o1 = offs[nd + 1];
        float acc = 0.f;
        if (c < 10) {
            int e = o0 + esub;
            for (; e + 4 < o1; e += 8) {
                int s0 = srt[e], s1 = srt[e + 4];
                acc += bf1(H[(size_t)s0 * 10 + c]) + bf1(H[(size_t)s1 * 10 + c]);
            }
            if (e < o1) acc += bf1(H[(size_t)srt[e] * 10 + c]);
        }
        acc += __shfl_xor(acc, 16);
        acc += __shfl_xor(acc, 32);
        if (esub == 0 && c < 10) {
            float dv = rsqrtf((float)(hist[nd] + 1));
            out[(size_t)d * 10 + c] = dv * (acc + bf1(H[(size_t)d * 10 + c])) + b3[c];
        }
    }
}

extern "C" void kernel_launch(void* const* d_in, const int* in_sizes, int n_in,
                              void* d_out, int out_size, void* d_ws, size_t ws_size,
                              hipStream_t stream) {
    const float* x  = (const float*)d_in[0];
    const int*   ei = (const int*)d_in[1];
    const float* W1 = (const float*)d_in[2];
    const float* b1 = (const float*)d_in[3];
    const float* W2 = (const float*)d_in[4];
    const float* b2 = (const float*)d_in[5];
    const float* W3 = (const float*)d_in[6];
    const float* b3 = (const float*)d_in[7];

    int N = in_sizes[0] / 128;
    int E = in_sizes[1] / 2;
    const int* esrc = ei;
    const int* edst = ei + E;
    int nb = (N + BK_NODES - 1) >> BK_SHIFT;

    char* p = (char*)d_ws;
    auto carve = [&](size_t bytes) -> void* {
        void* r = p;
        p += (bytes + 255) & ~(size_t)255;
        return r;
    };
    int*      cursor = (int*)carve((size_t)MAXNB * 4);
    unsigned* inter  = (unsigned*)carve((size_t)nb * BK_CAP * 4);
    float*    dinv   = (float*)carve((size_t)N * 4);
    unsigned short* Hs = (unsigned short*)carve((size_t)N * 64 * 2);  // bf16 table
    unsigned short* Gb = (unsigned short*)carve((size_t)N * 64 * 2);  // bf16 agg1 out
    float*    Gf     = (float*)carve((size_t)N * 64 * 4);             // f32 agg2 out
    unsigned short* Hs10 = (unsigned short*)carve((size_t)N * 10 * 2);
    (void)ws_size; (void)n_in; (void)out_size;

    hipMemsetAsync(cursor, 0, (size_t)nb * 4, stream);
    k_partition<<<(E + 16383) / 16384, 512, 0, stream>>>(esrc, edst, E, nb, cursor, inter);
    k_dinvb<<<nb, 256, 0, stream>>>(inter, cursor, dinv, N);

    // layer 1: Hs = bf16(dinv*(X @ W1)) ; Gb = bf16(relu(Agg(Hs)+b1))
    k_gemmMF<128, true><<<(N + 63) / 64, 256, 0, stream>>>(x, W1, dinv, Hs, N);
    k_agg64<1><<<nb, 512, 0, stream>>>(Hs, inter, cursor, b1, Gb, N, 1);
    // layer 2: Hs = bf16(dinv*(Gb @ W2)) ; Gf = relu(Agg(Hs)+b2)
    k_gemmMF<64, false><<<(N + 63) / 64, 256, 0, stream>>>(Gb, W2, dinv, Hs, N);
    k_agg64<0><<<nb, 512, 0, stream>>>(Hs, inter, cursor, b2, Gf, N, 1);
    // layer 3: Hs10 = bf16(dinv*(Gf @ W3)) ; out = Agg(Hs10) + b3
    k_gemm10<<<(N + 15) / 16, 256, 0, stream>>>(Gf, W3, dinv, Hs10, N);
    k_agg10<<<nb, 512, 0, stream>>>(Hs10, inter, cursor, b3, (float*)d_out, N);
}